// Round 5
// baseline (174.512 us; speedup 1.0000x reference)
//
#include <hip/hip_runtime.h>
#include <stdint.h>

// ---------------------------------------------------------------------------
// WeightGenerator_V4, round 4.
//   k1a: grouped 3x3 conv -> xr fp32. 128 blocks.
//   k1b: gate(1x1+BN+StarReLU) + dw3/dw5 + mul -> xc bf16; w_lin -> bf16.
//   k2a: Wd = xc @ w_lin^T (+b_lin) bf16. D tiles bounced through 64 KB LDS
//        so global stores are fully coalesced 64-B lines (write traffic
//        134 MB line-touches -> 67 MB).
//   k2b: out_patch = Wd_patch @ Y_patch. 48 KB LDS (Y 32 KB + 16 KB scratch,
//        4 staging passes w/ register prefetch) -> 3 blocks/CU x 8 waves.
//        Barrier-free K-loop; A streams from global; XCD block swizzle.
// ---------------------------------------------------------------------------

typedef __attribute__((ext_vector_type(8))) short short8;
typedef __attribute__((ext_vector_type(4))) float f32x4;

#define BN_EPS 1e-5f

__device__ __forceinline__ unsigned short f2bf(float f) {
  unsigned u = __float_as_uint(f);
  return (unsigned short)((u + 0x8000u) >> 16);
}
__device__ __forceinline__ unsigned pk2bf(float a, float b) {
  unsigned ua = __float_as_uint(a), ub = __float_as_uint(b);
  return ((ua + 0x8000u) >> 16) | ((ub + 0x8000u) & 0xFFFF0000u);
}

// =====================  k1a: grouped 3x3 conv -> xr  =====================
__global__ __launch_bounds__(256) void k1a_groupconv(
    const float* __restrict__ x, const float* __restrict__ w_cr,
    const float* __restrict__ b_cr, float* __restrict__ xr)
{
  __shared__ float xs[4][256];
  int b = blockIdx.x >> 6, cr = blockIdx.x & 63;
  int t = threadIdx.x;
  {
    int ch = t >> 6, off = (t & 63) * 4;
    float4 v = *(const float4*)(x + b * 65536 + (cr * 4 + ch) * 256 + off);
    *(float4*)&xs[ch][off] = v;
  }
  __syncthreads();
  int h = t >> 4, w = t & 15;
  float a = b_cr[cr];
  #pragma unroll
  for (int ii = 0; ii < 4; ++ii) {
    const float* wp = w_cr + (cr * 4 + ii) * 9;
    #pragma unroll
    for (int ky = 0; ky < 3; ++ky) {
      int gy = h + ky - 1;
      #pragma unroll
      for (int kx = 0; kx < 3; ++kx) {
        int gx = w + kx - 1;
        float v = (gy >= 0 && gy < 16 && gx >= 0 && gx < 16) ? xs[ii][gy * 16 + gx] : 0.f;
        a += wp[ky * 3 + kx] * v;
      }
    }
  }
  xr[(b * 64 + cr) * 256 + t] = a;
}

// =====================  k1b: gate + dw + multiply -> xc  =====================
__global__ __launch_bounds__(256) void k1b_gate_dw(
    const float* __restrict__ x, const float* __restrict__ xr,
    const float* __restrict__ w_dw3, const float* __restrict__ b_dw3,
    const float* __restrict__ w_dw7, const float* __restrict__ b_dw7,
    const float* __restrict__ w_gate, const float* __restrict__ b_gate,
    const float* __restrict__ bn_gamma, const float* __restrict__ bn_beta,
    const float* __restrict__ bn_mean, const float* __restrict__ bn_var,
    const float* __restrict__ sr_scale, const float* __restrict__ sr_bias,
    const float* __restrict__ w_lin, short* __restrict__ wlin_bf, short* __restrict__ xc_bf)
{
  __shared__ float xcen[256];
  __shared__ float gs[128];
  int blk = blockIdx.x;
  int b = blk >> 8, h = (blk >> 4) & 15, w = blk & 15;
  int t = threadIdx.x;

  { int idx = blk * 256 + t; wlin_bf[idx] = (short)f2bf(w_lin[idx]); }

  xcen[t] = x[b * 65536 + t * 256 + h * 16 + w];
  __syncthreads();

  int o = t >> 1, half = t & 1;
  {
    const float* wrow = w_gate + o * 256 + half * 128;
    const float* xcn  = xcen + half * 128;
    float ga = 0.f;
    #pragma unroll 8
    for (int ci = 0; ci < 128; ci += 4) {
      float4 wv = *(const float4*)(wrow + ci);
      float4 xv = *(const float4*)(xcn + ci);
      ga += wv.x * xv.x + wv.y * xv.y + wv.z * xv.z + wv.w * xv.w;
    }
    ga += __shfl_xor(ga, 1);
    float inv = bn_gamma[o] * rsqrtf(bn_var[o] + BN_EPS);
    float gg = (ga + b_gate[o] - bn_mean[o]) * inv + bn_beta[o];
    gg = fmaxf(gg, 0.f);
    gg = sr_scale[0] * gg * gg + sr_bias[0];
    if (half == 0) gs[o] = gg;
  }
  __syncthreads();

  if (t < 128) {
    int oc = t;
    float f0;
    if (oc < 64) {
      f0 = b_dw3[oc];
      const float* wp = w_dw3 + oc * 9;
      const float* xp = xr + (b * 64 + oc) * 256;
      #pragma unroll
      for (int ky = 0; ky < 3; ++ky) {
        int gy = h + ky - 1;
        #pragma unroll
        for (int kx = 0; kx < 3; ++kx) {
          int gx = w + kx - 1;
          float v = (gy >= 0 && gy < 16 && gx >= 0 && gx < 16) ? xp[gy * 16 + gx] : 0.f;
          f0 += wp[ky * 3 + kx] * v;
        }
      }
    } else {
      int c5 = oc - 64;
      f0 = b_dw7[c5];
      const float* wp = w_dw7 + c5 * 25;
      const float* xp = xr + (b * 64 + c5) * 256;
      #pragma unroll
      for (int ky = 0; ky < 5; ++ky) {
        int gy = h + ky - 2;
        #pragma unroll
        for (int kx = 0; kx < 5; ++kx) {
          int gx = w + kx - 2;
          float v = (gy >= 0 && gy < 16 && gx >= 0 && gx < 16) ? xp[gy * 16 + gx] : 0.f;
          f0 += wp[ky * 5 + kx] * v;
        }
      }
    }
    int pix = (b * 16 + h) * 16 + w;
    xc_bf[pix * 128 + oc] = (short)f2bf(f0 * gs[oc]);
  }
}

// =====================  k2a: Wd = xc @ w_lin^T (+b_lin), bf16  ==============
// 1024 blocks = 256 n-tiles x 4 o-chunks of 2048. Wave w covers o in
// [w*512,(w+1)*512). D tiles land in LDS; block then streams the 16n x 2048o
// bf16 tile to global with fully-coalesced uint2 stores (full 64-B lines).
__global__ __launch_bounds__(256) void k2a_wgen(
    const short* __restrict__ wlin_bf, const short* __restrict__ xc_bf,
    const float* __restrict__ b_lin, short* __restrict__ wd)
{
  __shared__ __align__(16) short Wt[16 * 2048];   // 64 KB
  int blk = blockIdx.x;
  int n0 = (blk >> 2) * 16;
  int oc = (blk & 3) * 2048;
  int tid = threadIdx.x;
  int wave = tid >> 6, lane = tid & 63;
  int quad = lane >> 4, l16 = lane & 15;

  // A[m=l16 -> n][k=quad*8+j] = xc[(n0+l16)*16 + k], k<16 (upper half zero)
  short8 af = {0, 0, 0, 0, 0, 0, 0, 0};
  if (quad < 2) af = *(const short8*)(xc_bf + (n0 + l16) * 16 + quad * 8);

  f32x4 zero4 = {0.f, 0.f, 0.f, 0.f};
  #pragma unroll 8
  for (int i = 0; i < 32; ++i) {
    int o0 = wave * 512 + i * 16;
    short8 bf = {0, 0, 0, 0, 0, 0, 0, 0};   // B[k=quad*8+j][n=l16 -> o]
    if (quad < 2) bf = *(const short8*)(wlin_bf + (oc + o0 + l16) * 16 + quad * 8);
    f32x4 d = __builtin_amdgcn_mfma_f32_16x16x32_bf16(af, bf, zero4, 0, 0, 0);
    float bl = b_lin[oc + o0 + l16];
    #pragma unroll
    for (int r = 0; r < 4; ++r)
      Wt[(quad * 4 + r) * 2048 + o0 + l16] = (short)f2bf(d[r] + bl);
  }
  __syncthreads();

  // coalesced store: 8192 uint2, 32 per thread; 512-B runs per wave
  const uint2* src = (const uint2*)Wt;
  #pragma unroll 8
  for (int j = 0; j < 32; ++j) {
    int fl = j * 256 + tid;            // uint2 index
    int row = fl >> 9;                 // 512 uint2 per 2048-short row
    int col = (fl & 511) * 4;          // short col within chunk
    *(uint2*)(wd + (size_t)(n0 + row) * 8192 + oc + col) = src[fl];
  }
}

// =====================  k2b: out = Wd @ Y per patch  =====================
// 512 blocks (XCD-swizzled), 512 threads = 8 waves (32 e-rows each).
// LDS: Ylds 32 KB + scratch 16 KB = 48 KB -> 3 blocks/CU, 24 waves/CU.
__global__ __launch_bounds__(512, 6) void k2b_dynconv(
    const float* __restrict__ y, const short* __restrict__ wd,
    float* __restrict__ out)
{
  __shared__ __align__(16) short Ylds[16384];   // [pix][256c] bf16, swizzled
  __shared__ __align__(16) float scratch[4096]; // [64c][64pix] fp32 per pass

  int phys = blockIdx.x;
  int blk = (phys & 7) * 64 + (phys >> 3);      // XCD-contiguous patches
  int b = blk >> 8, f = (blk >> 4) & 15, g = blk & 15;
  int tid = threadIdx.x;
  int wave = tid >> 6, lane = tid & 63;
  int quad = lane >> 4, l16 = lane & 15;

  const float* yb = y + b * 4194304 + (f * 8) * 128 + g * 8;
  const short* wdp = wd + (size_t)(((b * 16 + f) * 16 + g)) * 65536;

  // ---- stage Y: 4 passes of 64 channels, register-prefetched ----
  // per pass: 64c x 16 pixel-float4 = 1024 tasks -> 2 per thread
  int c_a = (tid >> 4) & 63;                    // task A: c for it=0 half? use explicit
  (void)c_a;
  float4 v0, v1, w0, w1;
  {
    int task0 = tid, task1 = 512 + tid;
    int ca = task0 >> 4, pfa = task0 & 15;
    int cb = task1 >> 4, pfb = task1 & 15;
    v0 = *(const float4*)(yb + ca * 16384 + (pfa >> 1) * 128 + (pfa & 1) * 4);
    v1 = *(const float4*)(yb + cb * 16384 + (pfb >> 1) * 128 + (pfb & 1) * 4);
  }
  for (int pass = 0; pass < 4; ++pass) {
    {
      int task0 = tid, task1 = 512 + tid;
      int ca = task0 >> 4, pfa = task0 & 15;
      int cb = task1 >> 4, pfb = task1 & 15;
      *(float4*)&scratch[ca * 64 + pfa * 4] = v0;
      *(float4*)&scratch[cb * 64 + pfb * 4] = v1;
      if (pass < 3) {
        w0 = *(const float4*)(yb + ((pass + 1) * 64 + ca) * 16384 + (pfa >> 1) * 128 + (pfa & 1) * 4);
        w1 = *(const float4*)(yb + ((pass + 1) * 64 + cb) * 16384 + (pfb >> 1) * 128 + (pfb & 1) * 4);
      }
    }
    __syncthreads();
    {
      int pix = tid & 63, cg = tid >> 6;        // 64 pix x 8 c-groups of 8
      float s0 = scratch[(cg * 8 + 0) * 64 + pix];
      float s1 = scratch[(cg * 8 + 1) * 64 + pix];
      float s2 = scratch[(cg * 8 + 2) * 64 + pix];
      float s3 = scratch[(cg * 8 + 3) * 64 + pix];
      float s4 = scratch[(cg * 8 + 4) * 64 + pix];
      float s5 = scratch[(cg * 8 + 5) * 64 + pix];
      float s6 = scratch[(cg * 8 + 6) * 64 + pix];
      float s7 = scratch[(cg * 8 + 7) * 64 + pix];
      uint4 pk;
      pk.x = pk2bf(s0, s1); pk.y = pk2bf(s2, s3);
      pk.z = pk2bf(s4, s5); pk.w = pk2bf(s6, s7);
      int chunk = pass * 8 + cg;                // 8-ch group id [0,32)
      int physc = chunk ^ (pix & 7);
      *(uint4*)&Ylds[pix * 256 + physc * 8] = pk;
    }
    __syncthreads();
    v0 = w0; v1 = w1;
  }

  // ---- barrier-free K-loop: 8 chunks of 32 channels, 2 e-tiles/wave ----
  f32x4 acc[2][4];
  f32x4 zero4 = {0.f, 0.f, 0.f, 0.f};
  #pragma unroll
  for (int et = 0; et < 2; ++et)
    #pragma unroll
    for (int nt = 0; nt < 4; ++nt)
      acc[et][nt] = zero4;

  #pragma unroll 2
  for (int cc = 0; cc < 8; ++cc) {
    short8 A[2], Bf[4];
    #pragma unroll
    for (int et = 0; et < 2; ++et) {
      int e = wave * 32 + et * 16 + l16;
      A[et] = *(const short8*)(wdp + e * 256 + cc * 32 + quad * 8);
    }
    int chunk = cc * 4 + quad;
    #pragma unroll
    for (int nt = 0; nt < 4; ++nt) {
      int nn = nt * 16 + l16;
      int physc = chunk ^ (nn & 7);
      Bf[nt] = *(const short8*)&Ylds[nn * 256 + physc * 8];
    }
    #pragma unroll
    for (int et = 0; et < 2; ++et)
      #pragma unroll
      for (int nt = 0; nt < 4; ++nt)
        acc[et][nt] = __builtin_amdgcn_mfma_f32_16x16x32_bf16(A[et], Bf[nt], acc[et][nt], 0, 0, 0);
  }

  // ---- epilogue: D row=quad*4+r -> e, col=l16 -> pix ----
  float* ob = out + b * 4194304 + (f * 8) * 128 + g * 8;
  #pragma unroll
  for (int et = 0; et < 2; ++et) {
    int e0 = wave * 32 + et * 16 + quad * 4;
    #pragma unroll
    for (int nt = 0; nt < 4; ++nt) {
      int pix = nt * 16 + l16;
      float* oa = ob + (pix >> 3) * 128 + (pix & 7);
      #pragma unroll
      for (int r = 0; r < 4; ++r)
        oa[(e0 + r) * 16384] = acc[et][nt][r];
    }
  }
}

// ============================  launcher  ============================
extern "C" void kernel_launch(void* const* d_in, const int* in_sizes, int n_in,
                              void* d_out, int out_size, void* d_ws, size_t ws_size,
                              hipStream_t stream) {
  const float* x        = (const float*)d_in[0];
  const float* y        = (const float*)d_in[1];
  const float* w_cr     = (const float*)d_in[2];
  const float* b_cr     = (const float*)d_in[3];
  const float* w_dw3    = (const float*)d_in[4];
  const float* b_dw3    = (const float*)d_in[5];
  const float* w_dw7    = (const float*)d_in[6];
  const float* b_dw7    = (const float*)d_in[7];
  const float* w_gate   = (const float*)d_in[8];
  const float* b_gate   = (const float*)d_in[9];
  const float* bn_gamma = (const float*)d_in[10];
  const float* bn_beta  = (const float*)d_in[11];
  const float* bn_mean  = (const float*)d_in[12];
  const float* bn_var   = (const float*)d_in[13];
  const float* sr_scale = (const float*)d_in[14];
  const float* sr_bias  = (const float*)d_in[15];
  const float* w_lin    = (const float*)d_in[16];
  const float* b_lin    = (const float*)d_in[17];
  float* out = (float*)d_out;

  // ws layout: xc_bf 128KB | wlin_bf 256KB | xr 128KB | Wd 64MB
  short* xc_bf   = (short*)d_ws;
  short* wlin_bf = (short*)((char*)d_ws + 131072);
  float* xr      = (float*)((char*)d_ws + 131072 + 262144);
  short* wd      = (short*)((char*)d_ws + 131072 + 262144 + 131072);

  hipLaunchKernelGGL(k1a_groupconv, dim3(128), dim3(256), 0, stream, x, w_cr, b_cr, xr);
  hipLaunchKernelGGL(k1b_gate_dw, dim3(512), dim3(256), 0, stream,
                     x, xr, w_dw3, b_dw3, w_dw7, b_dw7, w_gate, b_gate,
                     bn_gamma, bn_beta, bn_mean, bn_var, sr_scale, sr_bias,
                     w_lin, wlin_bf, xc_bf);
  hipLaunchKernelGGL(k2a_wgen, dim3(1024), dim3(256), 0, stream,
                     wlin_bf, xc_bf, b_lin, wd);
  hipLaunchKernelGGL(k2b_dynconv, dim3(512), dim3(512), 0, stream, y, wd, out);
}